// Round 1
// baseline (5279.819 us; speedup 1.0000x reference)
//
#include <hip/hip_runtime.h>

#define Cn 16
#define Bn 128
#define Hn 40
#define Wn 40
#define Sn 32
#define HID 128
#define PIX (Bn * Hn * Wn)          // 204800
#define NFRAME (Sn + 1)             // 33
#define RGB_TOTAL (NFRAME * PIX * 3)
#define STACK_FRAME (PIX * Cn)
#define ALPHA_T 0.1f

// ---------------------------------------------------------------------------
// Kernel A: per-pixel perception + MLP, produces pre-mask state P
//   P = S + upd_mask * (W2 @ relu(W1 @ perception + b1))
// Reads the alive mask of S from the precomputed field amF (written by the
// previous step_mask / init_am), so no 5x5 alpha gather here.
// Writes P (16ch) and the compact alpha plane Pa = P[...,3].
// ---------------------------------------------------------------------------
__global__ __launch_bounds__(256, 2) void step_update(
    const float* __restrict__ S,      // [PIX*16] current (already-masked) state
    const float* __restrict__ amF,    // [PIX] alive mask of S
    const int*   __restrict__ maskT,  // [PIX] update mask for this step
    float*       __restrict__ P,      // [PIX*16] out: pre-mask new state
    float*       __restrict__ Pa,     // [PIX] out: alpha plane of P
    const float* __restrict__ W1,     // [128*48]
    const float* __restrict__ b1,     // [128]
    const float* __restrict__ W2)     // [16*128]
{
    __shared__ float sW1[HID * 48];   // [j][48]
    __shared__ float sb1[HID];
    __shared__ float sW2T[HID * 16];  // transposed: [j][c]

    // ---- stage weights into LDS (coalesced) ----
    {
        const float4* w1v = (const float4*)W1;
        float4* s1v = (float4*)sW1;
        for (int i = threadIdx.x; i < HID * 48 / 4; i += 256) s1v[i] = w1v[i];
        if (threadIdx.x < HID / 4)
            ((float4*)sb1)[threadIdx.x] = ((const float4*)b1)[threadIdx.x];
        for (int i = threadIdx.x; i < HID * 16; i += 256) {
            int c = i >> 7;          // W2 is [16][128]
            int j = i & 127;
            sW2T[j * 16 + c] = W2[i];
        }
    }
    __syncthreads();

    int idx = blockIdx.x * 256 + threadIdx.x;   // PIX = 800*256 exactly
    int x  = idx % Wn;
    int t1 = idx / Wn;
    int y  = t1 % Hn;

    // ---- alive mask of the 3x3 neighborhood: read from field (coalesced) ----
    float am[3][3];
#pragma unroll
    for (int dy = 0; dy < 3; ++dy) {
#pragma unroll
        for (int dx = 0; dx < 3; ++dx) {
            int yy = y + dy - 1, xx = x + dx - 1;
            bool in = (yy >= 0) && (yy < Hn) && (xx >= 0) && (xx < Wn);
            am[dy][dx] = in ? amF[idx + (dy - 1) * Wn + (dx - 1)] : 0.f;
        }
    }

    // ---- perception: [masked(16) | sobel_x(16) | sobel_y(16)] ----
    float perc[48];
    float4 cen[4];
#pragma unroll
    for (int cg = 0; cg < 4; ++cg) {
        float4 m[3][3];
#pragma unroll
        for (int dy = 0; dy < 3; ++dy) {
#pragma unroll
            for (int dx = 0; dx < 3; ++dx) {
                int yy = y + dy - 1, xx = x + dx - 1;
                bool in = (yy >= 0) && (yy < Hn) && (xx >= 0) && (xx < Wn);
                float4 v;
                if (in) {
                    v = *(const float4*)&S[(idx + (dy - 1) * Wn + (dx - 1)) * Cn + cg * 4];
                    if (dy == 1 && dx == 1) cen[cg] = v;  // raw center (unmasked)
                    float a = am[dy][dx];
                    v.x *= a; v.y *= a; v.z *= a; v.w *= a;
                } else {
                    v.x = 0.f; v.y = 0.f; v.z = 0.f; v.w = 0.f;
                }
                m[dy][dx] = v;
            }
        }
        perc[cg * 4 + 0] = m[1][1].x;
        perc[cg * 4 + 1] = m[1][1].y;
        perc[cg * 4 + 2] = m[1][1].z;
        perc[cg * 4 + 3] = m[1][1].w;
        perc[16 + cg * 4 + 0] = ((m[0][2].x - m[0][0].x) + 2.f * (m[1][2].x - m[1][0].x) + (m[2][2].x - m[2][0].x)) * 0.125f;
        perc[16 + cg * 4 + 1] = ((m[0][2].y - m[0][0].y) + 2.f * (m[1][2].y - m[1][0].y) + (m[2][2].y - m[2][0].y)) * 0.125f;
        perc[16 + cg * 4 + 2] = ((m[0][2].z - m[0][0].z) + 2.f * (m[1][2].z - m[1][0].z) + (m[2][2].z - m[2][0].z)) * 0.125f;
        perc[16 + cg * 4 + 3] = ((m[0][2].w - m[0][0].w) + 2.f * (m[1][2].w - m[1][0].w) + (m[2][2].w - m[2][0].w)) * 0.125f;
        perc[32 + cg * 4 + 0] = ((m[2][0].x - m[0][0].x) + 2.f * (m[2][1].x - m[0][1].x) + (m[2][2].x - m[0][2].x)) * 0.125f;
        perc[32 + cg * 4 + 1] = ((m[2][0].y - m[0][0].y) + 2.f * (m[2][1].y - m[0][1].y) + (m[2][2].y - m[0][2].y)) * 0.125f;
        perc[32 + cg * 4 + 2] = ((m[2][0].z - m[0][0].z) + 2.f * (m[2][1].z - m[0][1].z) + (m[2][2].z - m[0][2].z)) * 0.125f;
        perc[32 + cg * 4 + 3] = ((m[2][0].w - m[0][0].w) + 2.f * (m[2][1].w - m[0][1].w) + (m[2][2].w - m[0][2].w)) * 0.125f;
    }

    // ---- MLP: hid = relu(W1 @ perc + b1); upd = W2 @ hid ----
    // W1/b1/W2T come from LDS via wave-uniform broadcast reads.
    // h uses 4-way split accumulation to cut the dependency chain 48 -> 12.
    float upd[16];
#pragma unroll
    for (int c = 0; c < 16; ++c) upd[c] = 0.f;

#pragma unroll 2
    for (int j = 0; j < HID; ++j) {
        const float4* w = (const float4*)(sW1 + j * 48);
        float hh0 = sb1[j], hh1 = 0.f, hh2 = 0.f, hh3 = 0.f;
        {
            float4 w0 = w[0], w1v = w[1], w2v = w[2];
            hh0 = fmaf(perc[0],  w0.x,  hh0); hh0 = fmaf(perc[1],  w0.y,  hh0);
            hh0 = fmaf(perc[2],  w0.z,  hh0); hh0 = fmaf(perc[3],  w0.w,  hh0);
            hh0 = fmaf(perc[4],  w1v.x, hh0); hh0 = fmaf(perc[5],  w1v.y, hh0);
            hh0 = fmaf(perc[6],  w1v.z, hh0); hh0 = fmaf(perc[7],  w1v.w, hh0);
            hh0 = fmaf(perc[8],  w2v.x, hh0); hh0 = fmaf(perc[9],  w2v.y, hh0);
            hh0 = fmaf(perc[10], w2v.z, hh0); hh0 = fmaf(perc[11], w2v.w, hh0);
        }
        {
            float4 w0 = w[3], w1v = w[4], w2v = w[5];
            hh1 = fmaf(perc[12], w0.x,  hh1); hh1 = fmaf(perc[13], w0.y,  hh1);
            hh1 = fmaf(perc[14], w0.z,  hh1); hh1 = fmaf(perc[15], w0.w,  hh1);
            hh1 = fmaf(perc[16], w1v.x, hh1); hh1 = fmaf(perc[17], w1v.y, hh1);
            hh1 = fmaf(perc[18], w1v.z, hh1); hh1 = fmaf(perc[19], w1v.w, hh1);
            hh1 = fmaf(perc[20], w2v.x, hh1); hh1 = fmaf(perc[21], w2v.y, hh1);
            hh1 = fmaf(perc[22], w2v.z, hh1); hh1 = fmaf(perc[23], w2v.w, hh1);
        }
        {
            float4 w0 = w[6], w1v = w[7], w2v = w[8];
            hh2 = fmaf(perc[24], w0.x,  hh2); hh2 = fmaf(perc[25], w0.y,  hh2);
            hh2 = fmaf(perc[26], w0.z,  hh2); hh2 = fmaf(perc[27], w0.w,  hh2);
            hh2 = fmaf(perc[28], w1v.x, hh2); hh2 = fmaf(perc[29], w1v.y, hh2);
            hh2 = fmaf(perc[30], w1v.z, hh2); hh2 = fmaf(perc[31], w1v.w, hh2);
            hh2 = fmaf(perc[32], w2v.x, hh2); hh2 = fmaf(perc[33], w2v.y, hh2);
            hh2 = fmaf(perc[34], w2v.z, hh2); hh2 = fmaf(perc[35], w2v.w, hh2);
        }
        {
            float4 w0 = w[9], w1v = w[10], w2v = w[11];
            hh3 = fmaf(perc[36], w0.x,  hh3); hh3 = fmaf(perc[37], w0.y,  hh3);
            hh3 = fmaf(perc[38], w0.z,  hh3); hh3 = fmaf(perc[39], w0.w,  hh3);
            hh3 = fmaf(perc[40], w1v.x, hh3); hh3 = fmaf(perc[41], w1v.y, hh3);
            hh3 = fmaf(perc[42], w1v.z, hh3); hh3 = fmaf(perc[43], w1v.w, hh3);
            hh3 = fmaf(perc[44], w2v.x, hh3); hh3 = fmaf(perc[45], w2v.y, hh3);
            hh3 = fmaf(perc[46], w2v.z, hh3); hh3 = fmaf(perc[47], w2v.w, hh3);
        }
        float h = fmaxf((hh0 + hh1) + (hh2 + hh3), 0.f);

        const float4* w2p = (const float4*)(sW2T + j * 16);
#pragma unroll
        for (int q = 0; q < 4; ++q) {
            float4 av = w2p[q];
            upd[q * 4 + 0] = fmaf(h, av.x, upd[q * 4 + 0]);
            upd[q * 4 + 1] = fmaf(h, av.y, upd[q * 4 + 1]);
            upd[q * 4 + 2] = fmaf(h, av.z, upd[q * 4 + 2]);
            upd[q * 4 + 3] = fmaf(h, av.w, upd[q * 4 + 3]);
        }
    }

    float fm = (float)maskT[idx];

#pragma unroll
    for (int cg = 0; cg < 4; ++cg) {
        float4 s = cen[cg];
        float4 o;
        o.x = s.x + upd[cg * 4 + 0] * fm;
        o.y = s.y + upd[cg * 4 + 1] * fm;
        o.z = s.z + upd[cg * 4 + 2] * fm;
        o.w = s.w + upd[cg * 4 + 3] * fm;
        *(float4*)&P[idx * Cn + cg * 4] = o;
        if (cg == 0) Pa[idx] = o.w;   // channel 3 = alpha
    }
}

// ---------------------------------------------------------------------------
// Kernel B: S_next = P * alive(P); also amNext = alive(S_next) for the next
// step's kernel A. Alpha gathered from the compact plane Pa (coalesced).
// ---------------------------------------------------------------------------
__global__ __launch_bounds__(256) void step_mask(
    const float* __restrict__ P,
    const float* __restrict__ Pa,
    float*       __restrict__ Snext,
    float*       __restrict__ amNext)
{
    int idx = blockIdx.x * 256 + threadIdx.x;
    int x  = idx % Wn;
    int t1 = idx / Wn;
    int y  = t1 % Hn;

    float a[5][5];
#pragma unroll
    for (int dy = 0; dy < 5; ++dy) {
#pragma unroll
        for (int dx = 0; dx < 5; ++dx) {
            int yy = y + dy - 2, xx = x + dx - 2;
            bool in = (yy >= 0) && (yy < Hn) && (xx >= 0) && (xx < Wn);
            a[dy][dx] = in ? Pa[idx + (dy - 2) * Wn + (dx - 2)] : -1e30f;
        }
    }

    float s[3][3];
    float aliveC = 0.f;
#pragma unroll
    for (int qy = 0; qy < 3; ++qy) {
#pragma unroll
        for (int qx = 0; qx < 3; ++qx) {
            float p = a[qy][qx];
            p = fmaxf(p, a[qy][qx + 1]);
            p = fmaxf(p, a[qy][qx + 2]);
            p = fmaxf(p, a[qy + 1][qx]);
            p = fmaxf(p, a[qy + 1][qx + 1]);
            p = fmaxf(p, a[qy + 1][qx + 2]);
            p = fmaxf(p, a[qy + 2][qx]);
            p = fmaxf(p, a[qy + 2][qx + 1]);
            p = fmaxf(p, a[qy + 2][qx + 2]);
            float alive = (p >= ALPHA_T) ? 1.f : 0.f;
            if (qy == 1 && qx == 1) aliveC = alive;
            int yy = y + qy - 1, xx = x + qx - 1;
            bool in = (yy >= 0) && (yy < Hn) && (xx >= 0) && (xx < Wn);
            // masked alpha of S_next at neighbor q; OOB pads with -inf
            s[qy][qx] = in ? a[qy + 1][qx + 1] * alive : -1e30f;
        }
    }

    float ps = s[0][0];
    ps = fmaxf(ps, s[0][1]); ps = fmaxf(ps, s[0][2]);
    ps = fmaxf(ps, s[1][0]); ps = fmaxf(ps, s[1][1]); ps = fmaxf(ps, s[1][2]);
    ps = fmaxf(ps, s[2][0]); ps = fmaxf(ps, s[2][1]); ps = fmaxf(ps, s[2][2]);
    float amN = (ps >= ALPHA_T) ? 1.f : 0.f;

#pragma unroll
    for (int cg = 0; cg < 4; ++cg) {
        float4 v = *(const float4*)&P[idx * Cn + cg * 4];
        v.x *= aliveC; v.y *= aliveC; v.z *= aliveC; v.w *= aliveC;
        *(float4*)&Snext[idx * Cn + cg * 4] = v;
    }
    amNext[idx] = amN;
}

// ---------------------------------------------------------------------------
// init_am: alive mask of the initial state (3x3 pooled alpha >= T)
// ---------------------------------------------------------------------------
__global__ __launch_bounds__(256) void init_am(
    const float* __restrict__ S0, float* __restrict__ amF)
{
    int idx = blockIdx.x * 256 + threadIdx.x;
    int x  = idx % Wn;
    int t1 = idx / Wn;
    int y  = t1 % Hn;
    float pooled = -1e30f;
#pragma unroll
    for (int dy = -1; dy <= 1; ++dy) {
#pragma unroll
        for (int dx = -1; dx <= 1; ++dx) {
            int yy = y + dy, xx = x + dx;
            bool in = (yy >= 0) && (yy < Hn) && (xx >= 0) && (xx < Wn);
            if (in) pooled = fmaxf(pooled, S0[(idx + dy * Wn + dx) * Cn + 3]);
        }
    }
    amF[idx] = (pooled >= ALPHA_T) ? 1.f : 0.f;
}

// ---------------------------------------------------------------------------
// Init copy: stacked[0] = initial_state
// ---------------------------------------------------------------------------
__global__ __launch_bounds__(256) void copy_init(
    const float4* __restrict__ src, float4* __restrict__ dst, int n4)
{
    int i = blockIdx.x * 256 + threadIdx.x;
    if (i < n4) dst[i] = src[i];
}

// ---------------------------------------------------------------------------
// RGB: rgb = trunc(clip(1 - clip(a,0,1) + rgb_ch, 0, 1) * 255), stored as f32
// ---------------------------------------------------------------------------
__global__ __launch_bounds__(256) void rgb_kernel(
    const float* __restrict__ stacked, float* __restrict__ rgb, int npix)
{
    int idx = blockIdx.x * 256 + threadIdx.x;
    if (idx >= npix) return;
    float4 s = *(const float4*)&stacked[idx * Cn];
    float a = fminf(fmaxf(s.w, 0.f), 1.f);
    float base = 1.f - a;
    rgb[idx * 3 + 0] = truncf(fminf(fmaxf(base + s.x, 0.f), 1.f) * 255.f);
    rgb[idx * 3 + 1] = truncf(fminf(fmaxf(base + s.y, 0.f), 1.f) * 255.f);
    rgb[idx * 3 + 2] = truncf(fminf(fmaxf(base + s.z, 0.f), 1.f) * 255.f);
}

extern "C" void kernel_launch(void* const* d_in, const int* in_sizes, int n_in,
                              void* d_out, int out_size, void* d_ws, size_t ws_size,
                              hipStream_t stream) {
    const float* init = (const float*)d_in[0];
    const float* W1   = (const float*)d_in[1];
    const float* b1   = (const float*)d_in[2];
    const float* W2   = (const float*)d_in[3];
    const int*   upd  = (const int*)d_in[4];

    float* out     = (float*)d_out;
    float* rgb     = out;                 // [NFRAME*PIX*3]
    float* stacked = out + RGB_TOTAL;     // [NFRAME*PIX*16]
    // Transient buffers staged in the rgb region (written last):
    //   P   : PIX*16 floats
    //   Pa  : PIX floats (alpha plane of P)
    //   amF : PIX floats (alive mask field of current S)
    // Total PIX*18 = 3.69M floats <= RGB_TOTAL (20.3M). OK.
    float* P   = out;
    float* Pa  = out + (size_t)PIX * Cn;
    float* amF = out + (size_t)PIX * (Cn + 1);

    const int blocks_pix = PIX / 256;     // 800, exact

    copy_init<<<(PIX * Cn / 4 + 255) / 256, 256, 0, stream>>>(
        (const float4*)init, (float4*)stacked, PIX * Cn / 4);
    init_am<<<blocks_pix, 256, 0, stream>>>(stacked, amF);

    for (int t = 0; t < Sn; ++t) {
        step_update<<<blocks_pix, 256, 0, stream>>>(
            stacked + (size_t)t * STACK_FRAME, amF, upd + (size_t)t * PIX,
            P, Pa, W1, b1, W2);
        step_mask<<<blocks_pix, 256, 0, stream>>>(
            P, Pa, stacked + (size_t)(t + 1) * STACK_FRAME, amF);
    }

    const int npix_all = NFRAME * PIX;
    rgb_kernel<<<(npix_all + 255) / 256, 256, 0, stream>>>(stacked, rgb, npix_all);
}

// Round 2
// 4015.046 us; speedup vs baseline: 1.3150x; 1.3150x over previous
//
#include <hip/hip_runtime.h>

#define Cn 16
#define Bn 128
#define Hn 40
#define Wn 40
#define Sn 32
#define HID 128
#define PIX (Bn * Hn * Wn)          // 204800
#define NFRAME (Sn + 1)             // 33
#define RGB_TOTAL (NFRAME * PIX * 3)
#define STACK_FRAME (PIX * Cn)
#define ALPHA_T 0.1f

// ---------------------------------------------------------------------------
// Kernel A: per-pixel perception + MLP, produces pre-mask state P
//   P = S + upd_mask * (W2 @ relu(W1 @ perception + b1))
// Weights are read with wave-UNIFORM addresses -> compiler emits s_load into
// SGPRs (scalar pipe, parallel to VALU). NO LDS in this kernel: LDS staging
// moved the weight reads onto the per-CU DS pipe and regressed (R1 post-mortem).
// W2T is the pre-transposed second layer: [j][c], one s_load_dwordx16 per j.
// ---------------------------------------------------------------------------
__global__ __launch_bounds__(256) void step_update(
    const float* __restrict__ S,      // [PIX*16] current (already-masked) state
    const float* __restrict__ amF,    // [PIX] alive mask of S
    const int*   __restrict__ maskT,  // [PIX] update mask for this step
    float*       __restrict__ P,      // [PIX*16] out: pre-mask new state
    float*       __restrict__ Pa,     // [PIX] out: alpha plane of P
    const float* __restrict__ W1,     // [128*48]
    const float* __restrict__ b1,     // [128]
    const float* __restrict__ W2T)    // [128*16] transposed second layer
{
    int idx = blockIdx.x * 256 + threadIdx.x;   // PIX = 800*256 exactly
    int x  = idx % Wn;
    int t1 = idx / Wn;
    int y  = t1 % Hn;

    // ---- alive mask of the 3x3 neighborhood: read from field (coalesced) ----
    float am[3][3];
#pragma unroll
    for (int dy = 0; dy < 3; ++dy) {
#pragma unroll
        for (int dx = 0; dx < 3; ++dx) {
            int yy = y + dy - 1, xx = x + dx - 1;
            bool in = (yy >= 0) && (yy < Hn) && (xx >= 0) && (xx < Wn);
            am[dy][dx] = in ? amF[idx + (dy - 1) * Wn + (dx - 1)] : 0.f;
        }
    }

    // ---- perception: [masked(16) | sobel_x(16) | sobel_y(16)] ----
    float perc[48];
    float4 cen[4];
#pragma unroll
    for (int cg = 0; cg < 4; ++cg) {
        float4 m[3][3];
#pragma unroll
        for (int dy = 0; dy < 3; ++dy) {
#pragma unroll
            for (int dx = 0; dx < 3; ++dx) {
                int yy = y + dy - 1, xx = x + dx - 1;
                bool in = (yy >= 0) && (yy < Hn) && (xx >= 0) && (xx < Wn);
                float4 v;
                if (in) {
                    v = *(const float4*)&S[(idx + (dy - 1) * Wn + (dx - 1)) * Cn + cg * 4];
                    if (dy == 1 && dx == 1) cen[cg] = v;  // raw center (unmasked)
                    float a = am[dy][dx];
                    v.x *= a; v.y *= a; v.z *= a; v.w *= a;
                } else {
                    v.x = 0.f; v.y = 0.f; v.z = 0.f; v.w = 0.f;
                }
                m[dy][dx] = v;
            }
        }
        perc[cg * 4 + 0] = m[1][1].x;
        perc[cg * 4 + 1] = m[1][1].y;
        perc[cg * 4 + 2] = m[1][1].z;
        perc[cg * 4 + 3] = m[1][1].w;
        perc[16 + cg * 4 + 0] = ((m[0][2].x - m[0][0].x) + 2.f * (m[1][2].x - m[1][0].x) + (m[2][2].x - m[2][0].x)) * 0.125f;
        perc[16 + cg * 4 + 1] = ((m[0][2].y - m[0][0].y) + 2.f * (m[1][2].y - m[1][0].y) + (m[2][2].y - m[2][0].y)) * 0.125f;
        perc[16 + cg * 4 + 2] = ((m[0][2].z - m[0][0].z) + 2.f * (m[1][2].z - m[1][0].z) + (m[2][2].z - m[2][0].z)) * 0.125f;
        perc[16 + cg * 4 + 3] = ((m[0][2].w - m[0][0].w) + 2.f * (m[1][2].w - m[1][0].w) + (m[2][2].w - m[2][0].w)) * 0.125f;
        perc[32 + cg * 4 + 0] = ((m[2][0].x - m[0][0].x) + 2.f * (m[2][1].x - m[0][1].x) + (m[2][2].x - m[0][2].x)) * 0.125f;
        perc[32 + cg * 4 + 1] = ((m[2][0].y - m[0][0].y) + 2.f * (m[2][1].y - m[0][1].y) + (m[2][2].y - m[0][2].y)) * 0.125f;
        perc[32 + cg * 4 + 2] = ((m[2][0].z - m[0][0].z) + 2.f * (m[2][1].z - m[0][1].z) + (m[2][2].z - m[0][2].z)) * 0.125f;
        perc[32 + cg * 4 + 3] = ((m[2][0].w - m[0][0].w) + 2.f * (m[2][1].w - m[0][1].w) + (m[2][2].w - m[0][2].w)) * 0.125f;
    }

    // ---- MLP: hid = relu(W1 @ perc + b1); upd = W2 @ hid ----
    // All weight accesses are wave-uniform -> s_load into SGPRs.
    // h uses 4-way split accumulation (dep chain 48 -> 12).
    float upd[16];
#pragma unroll
    for (int c = 0; c < 16; ++c) upd[c] = 0.f;

    for (int j = 0; j < HID; ++j) {
        const float* w = &W1[j * 48];
        float hh0 = b1[j], hh1 = 0.f, hh2 = 0.f, hh3 = 0.f;
#pragma unroll
        for (int i = 0; i < 12; ++i) {
            hh0 = fmaf(perc[i],      w[i],      hh0);
            hh1 = fmaf(perc[12 + i], w[12 + i], hh1);
            hh2 = fmaf(perc[24 + i], w[24 + i], hh2);
            hh3 = fmaf(perc[36 + i], w[36 + i], hh3);
        }
        float h = fmaxf((hh0 + hh1) + (hh2 + hh3), 0.f);

        const float* w2 = &W2T[j * 16];
#pragma unroll
        for (int c = 0; c < 16; ++c) upd[c] = fmaf(h, w2[c], upd[c]);
    }

    float fm = (float)maskT[idx];

#pragma unroll
    for (int cg = 0; cg < 4; ++cg) {
        float4 s = cen[cg];
        float4 o;
        o.x = s.x + upd[cg * 4 + 0] * fm;
        o.y = s.y + upd[cg * 4 + 1] * fm;
        o.z = s.z + upd[cg * 4 + 2] * fm;
        o.w = s.w + upd[cg * 4 + 3] * fm;
        *(float4*)&P[idx * Cn + cg * 4] = o;
        if (cg == 0) Pa[idx] = o.w;   // channel 3 = alpha
    }
}

// ---------------------------------------------------------------------------
// Kernel B: S_next = P * alive(P); also amNext = alive(S_next) for the next
// step's kernel A. Alpha gathered from the compact plane Pa (coalesced).
// ---------------------------------------------------------------------------
__global__ __launch_bounds__(256) void step_mask(
    const float* __restrict__ P,
    const float* __restrict__ Pa,
    float*       __restrict__ Snext,
    float*       __restrict__ amNext)
{
    int idx = blockIdx.x * 256 + threadIdx.x;
    int x  = idx % Wn;
    int t1 = idx / Wn;
    int y  = t1 % Hn;

    float a[5][5];
#pragma unroll
    for (int dy = 0; dy < 5; ++dy) {
#pragma unroll
        for (int dx = 0; dx < 5; ++dx) {
            int yy = y + dy - 2, xx = x + dx - 2;
            bool in = (yy >= 0) && (yy < Hn) && (xx >= 0) && (xx < Wn);
            a[dy][dx] = in ? Pa[idx + (dy - 2) * Wn + (dx - 2)] : -1e30f;
        }
    }

    float s[3][3];
    float aliveC = 0.f;
#pragma unroll
    for (int qy = 0; qy < 3; ++qy) {
#pragma unroll
        for (int qx = 0; qx < 3; ++qx) {
            float p = a[qy][qx];
            p = fmaxf(p, a[qy][qx + 1]);
            p = fmaxf(p, a[qy][qx + 2]);
            p = fmaxf(p, a[qy + 1][qx]);
            p = fmaxf(p, a[qy + 1][qx + 1]);
            p = fmaxf(p, a[qy + 1][qx + 2]);
            p = fmaxf(p, a[qy + 2][qx]);
            p = fmaxf(p, a[qy + 2][qx + 1]);
            p = fmaxf(p, a[qy + 2][qx + 2]);
            float alive = (p >= ALPHA_T) ? 1.f : 0.f;
            if (qy == 1 && qx == 1) aliveC = alive;
            int yy = y + qy - 1, xx = x + qx - 1;
            bool in = (yy >= 0) && (yy < Hn) && (xx >= 0) && (xx < Wn);
            // masked alpha of S_next at neighbor q; OOB pads with -inf
            s[qy][qx] = in ? a[qy + 1][qx + 1] * alive : -1e30f;
        }
    }

    float ps = s[0][0];
    ps = fmaxf(ps, s[0][1]); ps = fmaxf(ps, s[0][2]);
    ps = fmaxf(ps, s[1][0]); ps = fmaxf(ps, s[1][1]); ps = fmaxf(ps, s[1][2]);
    ps = fmaxf(ps, s[2][0]); ps = fmaxf(ps, s[2][1]); ps = fmaxf(ps, s[2][2]);
    float amN = (ps >= ALPHA_T) ? 1.f : 0.f;

#pragma unroll
    for (int cg = 0; cg < 4; ++cg) {
        float4 v = *(const float4*)&P[idx * Cn + cg * 4];
        v.x *= aliveC; v.y *= aliveC; v.z *= aliveC; v.w *= aliveC;
        *(float4*)&Snext[idx * Cn + cg * 4] = v;
    }
    amNext[idx] = amN;
}

// ---------------------------------------------------------------------------
// init_am: alive mask of the initial state (3x3 pooled alpha >= T)
// ---------------------------------------------------------------------------
__global__ __launch_bounds__(256) void init_am(
    const float* __restrict__ S0, float* __restrict__ amF)
{
    int idx = blockIdx.x * 256 + threadIdx.x;
    int x  = idx % Wn;
    int t1 = idx / Wn;
    int y  = t1 % Hn;
    float pooled = -1e30f;
#pragma unroll
    for (int dy = -1; dy <= 1; ++dy) {
#pragma unroll
        for (int dx = -1; dx <= 1; ++dx) {
            int yy = y + dy, xx = x + dx;
            bool in = (yy >= 0) && (yy < Hn) && (xx >= 0) && (xx < Wn);
            if (in) pooled = fmaxf(pooled, S0[(idx + dy * Wn + dx) * Cn + 3]);
        }
    }
    amF[idx] = (pooled >= ALPHA_T) ? 1.f : 0.f;
}

// ---------------------------------------------------------------------------
// transpose_w2: W2[16][128] -> W2T[128][16] so per-j reads are contiguous
// ---------------------------------------------------------------------------
__global__ __launch_bounds__(256) void transpose_w2(
    const float* __restrict__ W2, float* __restrict__ W2T)
{
    int i = blockIdx.x * 256 + threadIdx.x;
    if (i < Cn * HID) {
        int c = i >> 7;        // W2 row
        int j = i & 127;       // W2 col
        W2T[j * Cn + c] = W2[i];
    }
}

// ---------------------------------------------------------------------------
// Init copy: stacked[0] = initial_state
// ---------------------------------------------------------------------------
__global__ __launch_bounds__(256) void copy_init(
    const float4* __restrict__ src, float4* __restrict__ dst, int n4)
{
    int i = blockIdx.x * 256 + threadIdx.x;
    if (i < n4) dst[i] = src[i];
}

// ---------------------------------------------------------------------------
// RGB: rgb = trunc(clip(1 - clip(a,0,1) + rgb_ch, 0, 1) * 255), stored as f32
// ---------------------------------------------------------------------------
__global__ __launch_bounds__(256) void rgb_kernel(
    const float* __restrict__ stacked, float* __restrict__ rgb, int npix)
{
    int idx = blockIdx.x * 256 + threadIdx.x;
    if (idx >= npix) return;
    float4 s = *(const float4*)&stacked[idx * Cn];
    float a = fminf(fmaxf(s.w, 0.f), 1.f);
    float base = 1.f - a;
    rgb[idx * 3 + 0] = truncf(fminf(fmaxf(base + s.x, 0.f), 1.f) * 255.f);
    rgb[idx * 3 + 1] = truncf(fminf(fmaxf(base + s.y, 0.f), 1.f) * 255.f);
    rgb[idx * 3 + 2] = truncf(fminf(fmaxf(base + s.z, 0.f), 1.f) * 255.f);
}

extern "C" void kernel_launch(void* const* d_in, const int* in_sizes, int n_in,
                              void* d_out, int out_size, void* d_ws, size_t ws_size,
                              hipStream_t stream) {
    const float* init = (const float*)d_in[0];
    const float* W1   = (const float*)d_in[1];
    const float* b1   = (const float*)d_in[2];
    const float* W2   = (const float*)d_in[3];
    const int*   upd  = (const int*)d_in[4];

    float* out     = (float*)d_out;
    float* rgb     = out;                 // [NFRAME*PIX*3]
    float* stacked = out + RGB_TOTAL;     // [NFRAME*PIX*16]
    // Transient buffers staged in the rgb region (written last):
    //   P   : PIX*16 floats
    //   Pa  : PIX floats (alpha plane of P)
    //   amF : PIX floats (alive mask field of current S)
    //   W2T : 2048 floats (transposed second layer)
    // Total PIX*18 + 2048 = 3.69M floats <= RGB_TOTAL (20.3M). OK.
    float* P   = out;
    float* Pa  = out + (size_t)PIX * Cn;
    float* amF = out + (size_t)PIX * (Cn + 1);
    float* W2T = out + (size_t)PIX * (Cn + 2);

    const int blocks_pix = PIX / 256;     // 800, exact

    copy_init<<<(PIX * Cn / 4 + 255) / 256, 256, 0, stream>>>(
        (const float4*)init, (float4*)stacked, PIX * Cn / 4);
    init_am<<<blocks_pix, 256, 0, stream>>>(stacked, amF);
    transpose_w2<<<(Cn * HID + 255) / 256, 256, 0, stream>>>(W2, W2T);

    for (int t = 0; t < Sn; ++t) {
        step_update<<<blocks_pix, 256, 0, stream>>>(
            stacked + (size_t)t * STACK_FRAME, amF, upd + (size_t)t * PIX,
            P, Pa, W1, b1, W2T);
        step_mask<<<blocks_pix, 256, 0, stream>>>(
            P, Pa, stacked + (size_t)(t + 1) * STACK_FRAME, amF);
    }

    const int npix_all = NFRAME * PIX;
    rgb_kernel<<<(npix_all + 255) / 256, 256, 0, stream>>>(stacked, rgb, npix_all);
}